// Round 5
// baseline (361.009 us; speedup 1.0000x reference)
//
#include <hip/hip_runtime.h>
#include <stdint.h>

// ============================================================================
// LaneGraphConvLayerShared: NNConv(edge-conditioned) + root + residual + LN
//
// msg[e] = sum_{s<16} a[e,s]*(x[src]@W_s) + x[src]@B_bias   (B_bias = b_edge)
//
// R4 post-mortem: slot-split + cross-wave LDS reduce = 5 barriers/tile,
//   16K cy/tile-pair/CU, MfmaUtil 13%. R5: f-column split across waves --
//   wave w owns f in [16w,16w+16) with FULL K: B = 34 ksteps x 4 VGPR = 136
//   regs, NO cross-wave reduce, 2 barriers/tile. Per-slot y = MFMA(x_bf16,
//   W_s) then msg += a[e,s]*y as f32 scalar FMA (a exact in f32 now).
//   x staged in LDS as bf16 (converted once during staging).
// ============================================================================

typedef short short8 __attribute__((ext_vector_type(8)));
typedef float floatx4 __attribute__((ext_vector_type(4)));

__device__ __forceinline__ uint32_t cvt_pk_bf16(float lo, float hi) {
  uint32_t r;
  asm("v_cvt_pk_bf16_f32 %0, %1, %2" : "=v"(r) : "v"(lo), "v"(hi));
  return r;
}

__device__ __forceinline__ uint16_t f32_to_bf16_bits(float x) {
  uint32_t u = __float_as_uint(x);
  u += 0x7fffu + ((u >> 16) & 1u);
  return (uint16_t)(u >> 16);
}

// ws layout:
//   [0,        139264): W2frag  bf16 [slot17][kstep2][c4][lane64][i8]
//   [139264,   147456): Wsumfrag bf16 [kstep2][c4][lane64][i8]  (W_root+W_res)
//   [147456,   147712): bsum f32 [64]  (bias + b_res)
#define W2FRAG_OFF 0
#define WSUM_OFF   139264
#define BSUM_OFF   147456
#define PREP_TOTAL 73792   // 69632 + 4096 + 64

__global__ __launch_bounds__(256) void prep_kernel(
    const float* __restrict__ W_edge, const float* __restrict__ b_edge,
    const float* __restrict__ W_root, const float* __restrict__ bias,
    const float* __restrict__ W_res,  const float* __restrict__ b_res,
    uint16_t* __restrict__ w2frag, uint16_t* __restrict__ wsumfrag,
    float* __restrict__ bsum) {
  int gid = blockIdx.x * 256 + threadIdx.x;
  if (gid < 69632) {
    int i = gid & 7, l = (gid >> 3) & 63, c = (gid >> 9) & 3;
    int t = (gid >> 11) & 1, s = gid >> 12;
    int d = t * 32 + 8 * (l >> 4) + i;
    int f = c * 16 + (l & 15);
    float v = (s < 16) ? W_edge[s * 4096 + d * 64 + f] : b_edge[d * 64 + f];
    w2frag[gid] = f32_to_bf16_bits(v);
  } else if (gid < 73728) {
    int g = gid - 69632;
    int i = g & 7, l = (g >> 3) & 63, c = (g >> 9) & 3, t = (g >> 11) & 1;
    int d = t * 32 + 8 * (l >> 4) + i;
    int f = c * 16 + (l & 15);
    wsumfrag[g] = f32_to_bf16_bits(W_root[d * 64 + f] + W_res[d * 64 + f]);
  } else if (gid < PREP_TOTAL) {
    int f = gid - 73728;
    bsum[f] = bias[f] + b_res[f];
  }
}

// base: out[n,f] = sum_d x[n,d]*(W_root+W_res)[d,f] + bias[f]+b_res[f]
__global__ __launch_bounds__(256) void base_kernel(
    const float* __restrict__ x, const uint16_t* __restrict__ wsumfrag,
    const float* __restrict__ bsum, float* __restrict__ out, int N) {
  int w = threadIdx.x >> 6, l = threadIdx.x & 63;
  int l16 = l & 15, lq = l >> 4;
  int arow = blockIdx.x * 64 + w * 16 + l16;
  float xv[16];
#pragma unroll
  for (int t = 0; t < 2; ++t)
#pragma unroll
    for (int i = 0; i < 8; ++i)
      xv[t * 8 + i] = (arow < N) ? x[arow * 64 + t * 32 + 8 * lq + i] : 0.0f;
  union { short8 s8; uint32_t u[4]; } A[2];
#pragma unroll
  for (int t = 0; t < 2; ++t)
#pragma unroll
    for (int j = 0; j < 4; ++j)
      A[t].u[j] = cvt_pk_bf16(xv[t * 8 + 2 * j], xv[t * 8 + 2 * j + 1]);
  floatx4 acc[4];
#pragma unroll
  for (int c = 0; c < 4; ++c) acc[c] = (floatx4){0.f, 0.f, 0.f, 0.f};
  const short8* bp = (const short8*)wsumfrag;
#pragma unroll
  for (int t = 0; t < 2; ++t)
#pragma unroll
    for (int c = 0; c < 4; ++c) {
      short8 B = bp[(t * 4 + c) * 64 + l];
      acc[c] = __builtin_amdgcn_mfma_f32_16x16x32_bf16(A[t].s8, B, acc[c], 0, 0, 0);
    }
#pragma unroll
  for (int c = 0; c < 4; ++c) {
    int f = c * 16 + l16;
    float bs = bsum[f];
#pragma unroll
    for (int r = 0; r < 4; ++r) {
      int row = blockIdx.x * 64 + w * 16 + lq * 4 + r;
      if (row < N) out[row * 64 + f] = acc[c][r] + bs;
    }
  }
}

// edge: grid-stride over 64-edge tiles. Wave w owns f-cols [16w,16w+16) with
// full K (B = 136 VGPRs). Per slot: y = MFMA(x_bf,W_s), msg += a[e,s]*y (f32).
// No cross-wave reduce; 2 barriers/tile; line-coalesced atomic scatter.
__global__ __launch_bounds__(256, 2) void edge_kernel(
    const float* __restrict__ x, const int* __restrict__ eidx,
    const float* __restrict__ attr, const uint16_t* __restrict__ w2frag,
    float* __restrict__ out, int E) {
  __shared__ __align__(16) uint16_t xbf_lds[64][72];  // bf16, 144B rows (16B-aligned)
  __shared__ __align__(16) float a_lds[64][20];       // slots 0..15; 80B rows
  __shared__ int dst_lds[64];

  int tid = threadIdx.x;
  int w = tid >> 6, l = tid & 63, l16 = l & 15, lq = l >> 4;
  int row = tid >> 2, q = tid & 3;
  const int* srcp = eidx;
  const int* dstp = eidx + E;
  const float4* x4 = (const float4*)x;
  const float4* a4 = (const float4*)attr;
  int T = (E + 63) >> 6;
  const short8* bp = (const short8*)w2frag;

  // ---- B fragments -> registers: 34 ksteps (s,t), c = w (once per block) ----
  short8 Breg[34];
#pragma unroll
  for (int s = 0; s < 17; ++s)
#pragma unroll
    for (int t = 0; t < 2; ++t)
      Breg[s * 2 + t] = bp[((s * 2 + t) * 4 + w) * 64 + l];

  // ---- stage first tile ----
  int tl = blockIdx.x;
  if (tl < T) {
    int cnt0 = min(64, E - tl * 64);
    bool ok = row < cnt0;
    int sidx = ok ? srcp[tl * 64 + row] : 0;
    float4 v[4];
#pragma unroll
    for (int j = 0; j < 4; ++j) {
      v[j] = make_float4(0.f, 0.f, 0.f, 0.f);
      if (ok) v[j] = x4[sidx * 16 + q * 4 + j];
    }
    uint4 c0 = {cvt_pk_bf16(v[0].x, v[0].y), cvt_pk_bf16(v[0].z, v[0].w),
                cvt_pk_bf16(v[1].x, v[1].y), cvt_pk_bf16(v[1].z, v[1].w)};
    uint4 c1 = {cvt_pk_bf16(v[2].x, v[2].y), cvt_pk_bf16(v[2].z, v[2].w),
                cvt_pk_bf16(v[3].x, v[3].y), cvt_pk_bf16(v[3].z, v[3].w)};
    *(uint4*)&xbf_lds[row][q * 16] = c0;
    *(uint4*)&xbf_lds[row][q * 16 + 8] = c1;
    float4 av = make_float4(0.f, 0.f, 0.f, 0.f);
    if (ok) av = a4[(tl * 64 + row) * 4 + q];
    *(float4*)&a_lds[row][q * 4] = av;
    if (q == 0) dst_lds[row] = ok ? dstp[tl * 64 + row] : 0;
  }
  __syncthreads();

  for (; tl < T; tl += gridDim.x) {
    int cnt = min(64, E - tl * 64);
    int nxt = tl + (int)gridDim.x;
    bool havenxt = nxt < T;
    // early-issue next tile's gather (T14): consumed only at stage-write below
    float4 xr[4];
    float4 ar = make_float4(0.f, 0.f, 0.f, 0.f);
    int dv = 0;
    if (havenxt) {
      int cntn = min(64, E - nxt * 64);
      bool ok = row < cntn;
      int sidx = ok ? srcp[nxt * 64 + row] : 0;
#pragma unroll
      for (int j = 0; j < 4; ++j) {
        xr[j] = make_float4(0.f, 0.f, 0.f, 0.f);
        if (ok) xr[j] = x4[sidx * 16 + q * 4 + j];
      }
      if (ok) ar = a4[(nxt * 64 + row) * 4 + q];
      if (ok) dv = dstp[nxt * 64 + row];
    }

    // ---- compute: full tile, wave-private f-columns ----
    floatx4 acc[4];
#pragma unroll
    for (int rt = 0; rt < 4; ++rt) acc[rt] = (floatx4){0.f, 0.f, 0.f, 0.f};

#pragma unroll
    for (int rt = 0; rt < 4; ++rt) {
      int arow = rt * 16 + l16;
      short8 A0 = *(const short8*)&xbf_lds[arow][lq * 8];
      short8 A1 = *(const short8*)&xbf_lds[arow][32 + lq * 8];
#pragma unroll
      for (int g = 0; g < 4; ++g) {
        float4 av0 = *(const float4*)&a_lds[rt * 16 + lq * 4 + 0][g * 4];
        float4 av1 = *(const float4*)&a_lds[rt * 16 + lq * 4 + 1][g * 4];
        float4 av2 = *(const float4*)&a_lds[rt * 16 + lq * 4 + 2][g * 4];
        float4 av3 = *(const float4*)&a_lds[rt * 16 + lq * 4 + 3][g * 4];
#pragma unroll
        for (int sg = 0; sg < 4; ++sg) {
          int s = g * 4 + sg;
          floatx4 y = (floatx4){0.f, 0.f, 0.f, 0.f};
          y = __builtin_amdgcn_mfma_f32_16x16x32_bf16(A0, Breg[s * 2 + 0], y, 0, 0, 0);
          y = __builtin_amdgcn_mfma_f32_16x16x32_bf16(A1, Breg[s * 2 + 1], y, 0, 0, 0);
          float s0 = (sg == 0) ? av0.x : (sg == 1) ? av0.y : (sg == 2) ? av0.z : av0.w;
          float s1 = (sg == 0) ? av1.x : (sg == 1) ? av1.y : (sg == 2) ? av1.z : av1.w;
          float s2 = (sg == 0) ? av2.x : (sg == 1) ? av2.y : (sg == 2) ? av2.z : av2.w;
          float s3 = (sg == 0) ? av3.x : (sg == 1) ? av3.y : (sg == 2) ? av3.z : av3.w;
          acc[rt][0] += s0 * y[0];
          acc[rt][1] += s1 * y[1];
          acc[rt][2] += s2 * y[2];
          acc[rt][3] += s3 * y[3];
        }
      }
      {  // bias slot s=16, a == 1
        floatx4 y = (floatx4){0.f, 0.f, 0.f, 0.f};
        y = __builtin_amdgcn_mfma_f32_16x16x32_bf16(A0, Breg[32], y, 0, 0, 0);
        y = __builtin_amdgcn_mfma_f32_16x16x32_bf16(A1, Breg[33], y, 0, 0, 0);
        acc[rt] += y;
      }
    }

    // ---- line-coalesced atomic scatter: per instr 4 edges x 16 consec f ----
#pragma unroll
    for (int rt = 0; rt < 4; ++rt)
#pragma unroll
      for (int r = 0; r < 4; ++r) {
        int e = rt * 16 + lq * 4 + r;
        if (e < cnt) atomicAdd(&out[dst_lds[e] * 64 + w * 16 + l16], acc[rt][r]);
      }
    __syncthreads();  // all xbf/a reads done -> safe to overwrite

    // ---- stage next tile ----
    if (havenxt) {
      uint4 c0 = {cvt_pk_bf16(xr[0].x, xr[0].y), cvt_pk_bf16(xr[0].z, xr[0].w),
                  cvt_pk_bf16(xr[1].x, xr[1].y), cvt_pk_bf16(xr[1].z, xr[1].w)};
      uint4 c1 = {cvt_pk_bf16(xr[2].x, xr[2].y), cvt_pk_bf16(xr[2].z, xr[2].w),
                  cvt_pk_bf16(xr[3].x, xr[3].y), cvt_pk_bf16(xr[3].z, xr[3].w)};
      *(uint4*)&xbf_lds[row][q * 16] = c0;
      *(uint4*)&xbf_lds[row][q * 16 + 8] = c1;
      *(float4*)&a_lds[row][q * 4] = ar;
      if (q == 0) dst_lds[row] = dv;
    }
    __syncthreads();
  }
}

__global__ __launch_bounds__(256) void ln_kernel(
    float* __restrict__ out, const float* __restrict__ gamma,
    const float* __restrict__ beta, int N) {
  int w = threadIdx.x >> 6, l = threadIdx.x & 63;
  int row = blockIdx.x * 4 + w;
  if (row >= N) return;
  float v = out[row * 64 + l];
  float s = v;
#pragma unroll
  for (int m = 32; m >= 1; m >>= 1) s += __shfl_xor(s, m);
  float mu = s * 0.015625f;
  float d = v - mu;
  float q = d * d;
#pragma unroll
  for (int m = 32; m >= 1; m >>= 1) q += __shfl_xor(q, m);
  float var = q * 0.015625f;
  out[row * 64 + l] = d * rsqrtf(var + 1e-5f) * gamma[l] + beta[l];
}

extern "C" void kernel_launch(void* const* d_in, const int* in_sizes, int n_in,
                              void* d_out, int out_size, void* d_ws, size_t ws_size,
                              hipStream_t stream) {
  const float* x      = (const float*)d_in[0];
  const int*   eidx   = (const int*)d_in[1];
  const float* attr   = (const float*)d_in[2];
  const float* W_edge = (const float*)d_in[3];
  const float* b_edge = (const float*)d_in[4];
  const float* W_root = (const float*)d_in[5];
  const float* bias   = (const float*)d_in[6];
  const float* W_res  = (const float*)d_in[7];
  const float* b_res  = (const float*)d_in[8];
  const float* gamma  = (const float*)d_in[9];
  const float* beta   = (const float*)d_in[10];
  int N = in_sizes[0] / 64;
  int E = in_sizes[1] / 2;
  float* out = (float*)d_out;
  uint16_t* w2frag   = (uint16_t*)((char*)d_ws + W2FRAG_OFF);
  uint16_t* wsumfrag = (uint16_t*)((char*)d_ws + WSUM_OFF);
  float*    bsum     = (float*)((char*)d_ws + BSUM_OFF);

  prep_kernel<<<(PREP_TOTAL + 255) / 256, 256, 0, stream>>>(
      W_edge, b_edge, W_root, bias, W_res, b_res, w2frag, wsumfrag, bsum);
  base_kernel<<<(N + 63) / 64, 256, 0, stream>>>(x, wsumfrag, bsum, out, N);
  int T = (E + 63) / 64;
  int G = T < 512 ? T : 512;
  edge_kernel<<<G, 256, 0, stream>>>(x, eidx, attr, w2frag, out, E);
  ln_kernel<<<(N + 3) / 4, 256, 0, stream>>>(out, gamma, beta, N);
}

// Round 6
// 331.047 us; speedup vs baseline: 1.0905x; 1.0905x over previous
//
#include <hip/hip_runtime.h>
#include <stdint.h>

// ============================================================================
// LaneGraphConvLayerShared: NNConv(edge-conditioned) + root + residual + LN
//
// msg[e] = sum_{s<16} a[e,s]*(x[src]@W_s) + x[src]@Bb   (Bb = reshape(b_edge))
//
// R5 post-mortem: Breg[34] (136 VGPR) under a 128-VGPR allocator cap ->
//   full spill to scratch (FETCH 410MB / WRITE 559MB, 337us). R4's VGPR=128
//   shows its "register B" was silently rematerialized from L2 too (-> 63us
//   wall shared with R0).
// R6: B lives in LDS, staged ONCE per block (slots 0-15 = 131KB; bias slot in
//   8 VGPRs). 256 blocks grid-stride 128-edge tiles. Wave w owns f-cols
//   [16w,16w+16): one B-frag ds_read serves 8 row-group MFMAs. x staged bf16
//   with XOR swizzle (T2), a in padded LDS, 2 barriers/tile, early-issued
//   gathers (T14). amdgpu_waves_per_eu(1,1) opens the register budget
//   (1 block/CU anyway) -> no spill. Line-coalesced atomic scatter kept.
// ============================================================================

#define TE 128
#define PREP_ELEMS 69632
#define PREP_BLOCKS 272  // ceil(69632/256)
#define SMEM_BYTES (131072 + 16384 + 10240 + 512)

typedef short short8 __attribute__((ext_vector_type(8)));
typedef float floatx4 __attribute__((ext_vector_type(4)));

__device__ __forceinline__ uint32_t cvt_pk_bf16(float lo, float hi) {
  uint32_t r;
  asm("v_cvt_pk_bf16_f32 %0, %1, %2" : "=v"(r) : "v"(lo), "v"(hi));
  return r;
}

__device__ __forceinline__ uint16_t f32_to_bf16_bits(float x) {
  uint32_t u = __float_as_uint(x);
  u += 0x7fffu + ((u >> 16) & 1u);
  return (uint16_t)(u >> 16);
}

__device__ __forceinline__ float f4_get(const float4& v, int i) {
  return i == 0 ? v.x : i == 1 ? v.y : i == 2 ? v.z : v.w;
}

// K1: blocks [0,PREP_BLOCKS) build w2frag bf16 [s17][t2][c4][lane64][i8];
//     blocks [PREP_BLOCKS, ...) do base: out = x@(W_root+W_res) + bias+b_res.
__global__ __launch_bounds__(256) void k1_kernel(
    const float* __restrict__ x,
    const float* __restrict__ W_edge, const float* __restrict__ b_edge,
    const float* __restrict__ W_root, const float* __restrict__ bias,
    const float* __restrict__ W_res,  const float* __restrict__ b_res,
    uint16_t* __restrict__ w2frag, float* __restrict__ out, int N) {
  int tid = threadIdx.x;
  if (blockIdx.x < PREP_BLOCKS) {
    int gid = blockIdx.x * 256 + tid;
    if (gid < PREP_ELEMS) {
      int i = gid & 7, l = (gid >> 3) & 63, c = (gid >> 9) & 3;
      int t = (gid >> 11) & 1, s = gid >> 12;
      int d = t * 32 + 8 * (l >> 4) + i;
      int f = c * 16 + (l & 15);
      float v = (s < 16) ? W_edge[s * 4096 + d * 64 + f] : b_edge[d * 64 + f];
      w2frag[gid] = f32_to_bf16_bits(v);
    }
    return;
  }
  int bb = blockIdx.x - PREP_BLOCKS;
  int w = tid >> 6, l = tid & 63, l16 = l & 15, lq = l >> 4;
  // build Wsum B-frags inline (W_root/W_res are L1/L2-hot 16KB arrays)
  union BF { short8 s8; uint16_t h[8]; } Bf[2][4];
#pragma unroll
  for (int t = 0; t < 2; ++t)
#pragma unroll
    for (int c = 0; c < 4; ++c)
#pragma unroll
      for (int i = 0; i < 8; ++i) {
        int d = t * 32 + 8 * lq + i;
        int f = c * 16 + l16;
        Bf[t][c].h[i] = f32_to_bf16_bits(W_root[d * 64 + f] + W_res[d * 64 + f]);
      }
  int arow = bb * 64 + w * 16 + l16;
  float xv[16];
#pragma unroll
  for (int t = 0; t < 2; ++t)
#pragma unroll
    for (int i = 0; i < 8; ++i)
      xv[t * 8 + i] = (arow < N) ? x[arow * 64 + t * 32 + 8 * lq + i] : 0.0f;
  union { short8 s8; uint32_t u[4]; } A[2];
#pragma unroll
  for (int t = 0; t < 2; ++t)
#pragma unroll
    for (int j = 0; j < 4; ++j)
      A[t].u[j] = cvt_pk_bf16(xv[t * 8 + 2 * j], xv[t * 8 + 2 * j + 1]);
  floatx4 acc[4];
#pragma unroll
  for (int c = 0; c < 4; ++c) acc[c] = (floatx4){0.f, 0.f, 0.f, 0.f};
#pragma unroll
  for (int t = 0; t < 2; ++t)
#pragma unroll
    for (int c = 0; c < 4; ++c)
      acc[c] = __builtin_amdgcn_mfma_f32_16x16x32_bf16(A[t].s8, Bf[t][c].s8, acc[c], 0, 0, 0);
#pragma unroll
  for (int c = 0; c < 4; ++c) {
    int f = c * 16 + l16;
    float bs = bias[f] + b_res[f];
#pragma unroll
    for (int r = 0; r < 4; ++r) {
      int row = bb * 64 + w * 16 + lq * 4 + r;
      if (row < N) out[row * 64 + f] = acc[c][r] + bs;
    }
  }
}

// edge kernel: B in LDS (once/block), 128-edge tiles, wave-private f-columns.
__global__ __launch_bounds__(256) __attribute__((amdgpu_waves_per_eu(1, 1)))
void edge_kernel(const float* __restrict__ x, const int* __restrict__ eidx,
                 const float* __restrict__ attr, const uint16_t* __restrict__ w2frag,
                 float* __restrict__ out, int E, int T) {
  extern __shared__ char smem[];
  uint16_t* B_lds = (uint16_t*)smem;                            // 131072 B
  char* xb = smem + 131072;                                     // bf16 [128][64] ^swz, 16384 B
  float (*a_lds)[20] = (float(*)[20])(smem + 131072 + 16384);   // 10240 B
  int* dst_lds = (int*)(smem + 131072 + 16384 + 10240);         // 512 B

  int tid = threadIdx.x;
  int w = tid >> 6, l = tid & 63, l16 = l & 15, lq = l >> 4;
  const int* srcp = eidx;
  const int* dstp = eidx + E;
  const float4* x4 = (const float4*)x;
  const float4* a4 = (const float4*)attr;

  // ---- stage B (slots 0..15, 131072 B) linearly, once per block ----
  {
    const uint4* s = (const uint4*)w2frag;
    uint4* d = (uint4*)B_lds;
#pragma unroll
    for (int it = 0; it < 32; ++it) d[it * 256 + tid] = s[it * 256 + tid];
  }
  // bias-slot (s=16) frags in registers
  const short8* bp = (const short8*)w2frag;
  short8 Bb0 = bp[(32 * 4 + w) * 64 + l];
  short8 Bb1 = bp[(33 * 4 + w) * 64 + l];

  int row = tid >> 1, half = tid & 1;
  int swzw = (row & 7) << 4;

  // ---- prologue: stage tile blockIdx.x ----
  {
    int eg = min(blockIdx.x * TE + row, E - 1);
    int sidx = srcp[eg];
    float4 xr[8];
#pragma unroll
    for (int j = 0; j < 8; ++j) xr[j] = x4[sidx * 16 + half * 8 + j];
    float4 a0 = a4[eg * 4 + half * 2];
    float4 a1 = a4[eg * 4 + half * 2 + 1];
#pragma unroll
    for (int j = 0; j < 4; ++j) {
      uint4 c;
      c.x = cvt_pk_bf16(xr[2 * j].x, xr[2 * j].y);
      c.y = cvt_pk_bf16(xr[2 * j].z, xr[2 * j].w);
      c.z = cvt_pk_bf16(xr[2 * j + 1].x, xr[2 * j + 1].y);
      c.w = cvt_pk_bf16(xr[2 * j + 1].z, xr[2 * j + 1].w);
      *(uint4*)(xb + ((row * 128 + half * 64 + j * 16) ^ swzw)) = c;
    }
    *(float4*)&a_lds[row][half * 8] = a0;
    *(float4*)&a_lds[row][half * 8 + 4] = a1;
    if (tid < TE) dst_lds[tid] = dstp[min((int)blockIdx.x * TE + tid, E - 1)];
  }
  __syncthreads();

  for (int tl = blockIdx.x; tl < T; tl += gridDim.x) {
    int cnt = min(TE, E - tl * TE);
    int nxt = tl + (int)gridDim.x;
    bool havenxt = nxt < T;

    // early-issue next tile's gathers (consumed after the post-compute barrier)
    float4 xr[8], ar0, ar1;
    int dv = 0;
    if (havenxt) {
      int eg = min(nxt * TE + row, E - 1);
      int sidx = srcp[eg];
#pragma unroll
      for (int j = 0; j < 8; ++j) xr[j] = x4[sidx * 16 + half * 8 + j];
      ar0 = a4[eg * 4 + half * 2];
      ar1 = a4[eg * 4 + half * 2 + 1];
      if (tid < TE) dv = dstp[min(nxt * TE + tid, E - 1)];
    }

    // A-frags for 8 row-groups (swizzled reads, conflict-free)
    short8 A[8][2];
    int swzr = (l16 & 7) << 4;
#pragma unroll
    for (int rt = 0; rt < 8; ++rt) {
      int ab = (rt * 16 + l16) * 128;
      A[rt][0] = *(const short8*)(xb + ((ab + lq * 16) ^ swzr));
      A[rt][1] = *(const short8*)(xb + ((ab + 64 + lq * 16) ^ swzr));
    }

    floatx4 acc[8];
#pragma unroll
    for (int rt = 0; rt < 8; ++rt) acc[rt] = (floatx4){0.f, 0.f, 0.f, 0.f};

    const short8* BL = (const short8*)B_lds;
#pragma unroll
    for (int g = 0; g < 4; ++g) {
      short8 Bf[4][2];
#pragma unroll
      for (int sg = 0; sg < 4; ++sg) {
        int s = g * 4 + sg;
        Bf[sg][0] = BL[((s * 2 + 0) * 4 + w) * 64 + l];
        Bf[sg][1] = BL[((s * 2 + 1) * 4 + w) * 64 + l];
      }
#pragma unroll
      for (int rt = 0; rt < 8; ++rt) {
        float4 av[4];
#pragma unroll
        for (int r = 0; r < 4; ++r)
          av[r] = *(const float4*)&a_lds[rt * 16 + lq * 4 + r][g * 4];
#pragma unroll
        for (int sg = 0; sg < 4; ++sg) {
          floatx4 y = (floatx4){0.f, 0.f, 0.f, 0.f};
          y = __builtin_amdgcn_mfma_f32_16x16x32_bf16(A[rt][1], Bf[sg][1], y, 0, 0, 0);
          y = __builtin_amdgcn_mfma_f32_16x16x32_bf16(A[rt][0], Bf[sg][0], y, 0, 0, 0);
          acc[rt][0] += f4_get(av[0], sg) * y[0];
          acc[rt][1] += f4_get(av[1], sg) * y[1];
          acc[rt][2] += f4_get(av[2], sg) * y[2];
          acc[rt][3] += f4_get(av[3], sg) * y[3];
        }
      }
    }
    // bias slot (a == 1)
#pragma unroll
    for (int rt = 0; rt < 8; ++rt) {
      floatx4 y = (floatx4){0.f, 0.f, 0.f, 0.f};
      y = __builtin_amdgcn_mfma_f32_16x16x32_bf16(A[rt][1], Bb1, y, 0, 0, 0);
      y = __builtin_amdgcn_mfma_f32_16x16x32_bf16(A[rt][0], Bb0, y, 0, 0, 0);
      acc[rt] += y;
    }

    // line-coalesced atomic scatter: per instr 4 edges x 16 consecutive f
#pragma unroll
    for (int rt = 0; rt < 8; ++rt)
#pragma unroll
      for (int r = 0; r < 4; ++r) {
        int e = rt * 16 + lq * 4 + r;
        if (e < cnt) atomicAdd(&out[dst_lds[e] * 64 + w * 16 + l16], acc[rt][r]);
      }
    __syncthreads();  // all x/a/dst reads done -> safe to overwrite staging

    if (havenxt) {
#pragma unroll
      for (int j = 0; j < 4; ++j) {
        uint4 c;
        c.x = cvt_pk_bf16(xr[2 * j].x, xr[2 * j].y);
        c.y = cvt_pk_bf16(xr[2 * j].z, xr[2 * j].w);
        c.z = cvt_pk_bf16(xr[2 * j + 1].x, xr[2 * j + 1].y);
        c.w = cvt_pk_bf16(xr[2 * j + 1].z, xr[2 * j + 1].w);
        *(uint4*)(xb + ((row * 128 + half * 64 + j * 16) ^ swzw)) = c;
      }
      *(float4*)&a_lds[row][half * 8] = ar0;
      *(float4*)&a_lds[row][half * 8 + 4] = ar1;
      if (tid < TE) dst_lds[tid] = dv;
    }
    __syncthreads();
  }
}

__global__ __launch_bounds__(256) void ln_kernel(
    float* __restrict__ out, const float* __restrict__ gamma,
    const float* __restrict__ beta, int N) {
  int w = threadIdx.x >> 6, l = threadIdx.x & 63;
  int row = blockIdx.x * 4 + w;
  if (row >= N) return;
  float v = out[row * 64 + l];
  float s = v;
#pragma unroll
  for (int m = 32; m >= 1; m >>= 1) s += __shfl_xor(s, m);
  float mu = s * 0.015625f;
  float d = v - mu;
  float q = d * d;
#pragma unroll
  for (int m = 32; m >= 1; m >>= 1) q += __shfl_xor(q, m);
  float var = q * 0.015625f;
  out[row * 64 + l] = d * rsqrtf(var + 1e-5f) * gamma[l] + beta[l];
}

extern "C" void kernel_launch(void* const* d_in, const int* in_sizes, int n_in,
                              void* d_out, int out_size, void* d_ws, size_t ws_size,
                              hipStream_t stream) {
  const float* x      = (const float*)d_in[0];
  const int*   eidx   = (const int*)d_in[1];
  const float* attr   = (const float*)d_in[2];
  const float* W_edge = (const float*)d_in[3];
  const float* b_edge = (const float*)d_in[4];
  const float* W_root = (const float*)d_in[5];
  const float* bias   = (const float*)d_in[6];
  const float* W_res  = (const float*)d_in[7];
  const float* b_res  = (const float*)d_in[8];
  const float* gamma  = (const float*)d_in[9];
  const float* beta   = (const float*)d_in[10];
  int N = in_sizes[0] / 64;
  int E = in_sizes[1] / 2;
  float* out = (float*)d_out;
  uint16_t* w2frag = (uint16_t*)d_ws;

  int G1 = PREP_BLOCKS + (N + 63) / 64;
  k1_kernel<<<G1, 256, 0, stream>>>(x, W_edge, b_edge, W_root, bias, W_res,
                                    b_res, w2frag, out, N);
  int T = (E + TE - 1) / TE;
  int G = T < 256 ? T : 256;
  (void)hipFuncSetAttribute((const void*)edge_kernel,
                            hipFuncAttributeMaxDynamicSharedMemorySize,
                            SMEM_BYTES);
  edge_kernel<<<G, 256, SMEM_BYTES, stream>>>(x, eidx, attr, w2frag, out, E, T);
  ln_kernel<<<(N + 3) / 4, 256, 0, stream>>>(out, gamma, beta, N);
}

// Round 7
// 95.135 us; speedup vs baseline: 3.7947x; 3.4798x over previous
//
#include <hip/hip_runtime.h>
#include <stdint.h>

// ============================================================================
// LaneGraphConvLayerShared: NNConv(edge-conditioned) + root + residual + LN
//
// msg[e] = sum_{s<16} a[e,s]*(x[src]@W_s) + x[src]@Bb   (Bb = reshape(b_edge))
//
// R5/R6 post-mortem: register-resident / LDS-resident B both spill or kill
//   occupancy (>128 live VGPRs -> ~1GB scratch traffic; 158KB LDS -> 1
//   block/CU). R0/R4's 63us wall = L2 latency on B-loads with 4x wave
//   duplication + per-slot A rebuild VALU.
// R7: one 64-edge tile per block (2344 blocks), B STREAMED from L2 per tile
//   but: (1) f-column split across waves (wave w owns f=[16w,16w+16)) -> 34
//   B-loads/wave, no duplication; (2) per-slot y=MFMA(x_bf,W_s) + f32 a-scale
//   -> A-frags built once (8 swizzled ds_read_b128), 272 v_fma/wave; (3)
//   small regs (~120 VGPR), 13.5KB LDS -> ~4 blocks/CU TLP hides latency.
//   Line-coalesced atomic scatter (R4-verified, ~4B/atomic writeback).
// ============================================================================

#define PREP_ELEMS 69632
#define PREP_BLOCKS 272  // ceil(69632/256)

typedef short short8 __attribute__((ext_vector_type(8)));
typedef float floatx4 __attribute__((ext_vector_type(4)));

__device__ __forceinline__ uint32_t cvt_pk_bf16(float lo, float hi) {
  uint32_t r;
  asm("v_cvt_pk_bf16_f32 %0, %1, %2" : "=v"(r) : "v"(lo), "v"(hi));
  return r;
}

__device__ __forceinline__ uint16_t f32_to_bf16_bits(float x) {
  uint32_t u = __float_as_uint(x);
  u += 0x7fffu + ((u >> 16) & 1u);
  return (uint16_t)(u >> 16);
}

__device__ __forceinline__ float f4_get(const float4& v, int i) {
  return i == 0 ? v.x : i == 1 ? v.y : i == 2 ? v.z : v.w;
}

// K1: blocks [0,PREP_BLOCKS) build w2frag bf16 [s17][t2][c4][lane64][i8];
//     blocks [PREP_BLOCKS, ...) do base: out = x@(W_root+W_res) + bias+b_res.
__global__ __launch_bounds__(256) void k1_kernel(
    const float* __restrict__ x,
    const float* __restrict__ W_edge, const float* __restrict__ b_edge,
    const float* __restrict__ W_root, const float* __restrict__ bias,
    const float* __restrict__ W_res,  const float* __restrict__ b_res,
    uint16_t* __restrict__ w2frag, float* __restrict__ out, int N) {
  int tid = threadIdx.x;
  if (blockIdx.x < PREP_BLOCKS) {
    int gid = blockIdx.x * 256 + tid;
    if (gid < PREP_ELEMS) {
      int i = gid & 7, l = (gid >> 3) & 63, c = (gid >> 9) & 3;
      int t = (gid >> 11) & 1, s = gid >> 12;
      int d = t * 32 + 8 * (l >> 4) + i;
      int f = c * 16 + (l & 15);
      float v = (s < 16) ? W_edge[s * 4096 + d * 64 + f] : b_edge[d * 64 + f];
      w2frag[gid] = f32_to_bf16_bits(v);
    }
    return;
  }
  int bb = blockIdx.x - PREP_BLOCKS;
  int w = tid >> 6, l = tid & 63, l16 = l & 15, lq = l >> 4;
  union BF { short8 s8; uint16_t h[8]; } Bf[2][4];
#pragma unroll
  for (int t = 0; t < 2; ++t)
#pragma unroll
    for (int c = 0; c < 4; ++c)
#pragma unroll
      for (int i = 0; i < 8; ++i) {
        int d = t * 32 + 8 * lq + i;
        int f = c * 16 + l16;
        Bf[t][c].h[i] = f32_to_bf16_bits(W_root[d * 64 + f] + W_res[d * 64 + f]);
      }
  int arow = bb * 64 + w * 16 + l16;
  float xv[16];
#pragma unroll
  for (int t = 0; t < 2; ++t)
#pragma unroll
    for (int i = 0; i < 8; ++i)
      xv[t * 8 + i] = (arow < N) ? x[arow * 64 + t * 32 + 8 * lq + i] : 0.0f;
  union { short8 s8; uint32_t u[4]; } A[2];
#pragma unroll
  for (int t = 0; t < 2; ++t)
#pragma unroll
    for (int j = 0; j < 4; ++j)
      A[t].u[j] = cvt_pk_bf16(xv[t * 8 + 2 * j], xv[t * 8 + 2 * j + 1]);
  floatx4 acc[4];
#pragma unroll
  for (int c = 0; c < 4; ++c) acc[c] = (floatx4){0.f, 0.f, 0.f, 0.f};
#pragma unroll
  for (int t = 0; t < 2; ++t)
#pragma unroll
    for (int c = 0; c < 4; ++c)
      acc[c] = __builtin_amdgcn_mfma_f32_16x16x32_bf16(A[t].s8, Bf[t][c].s8, acc[c], 0, 0, 0);
#pragma unroll
  for (int c = 0; c < 4; ++c) {
    int f = c * 16 + l16;
    float bs = bias[f] + b_res[f];
#pragma unroll
    for (int r = 0; r < 4; ++r) {
      int row = bb * 64 + w * 16 + lq * 4 + r;
      if (row < N) out[row * 64 + f] = acc[c][r] + bs;
    }
  }
}

// edge: one 64-edge tile per block. Wave w owns f-cols [16w,16w+16), full K.
// B streamed from L2 (34 coalesced b128/lane-wave); A-frags from swizzled LDS.
__global__ __launch_bounds__(256) void edge_kernel(
    const float* __restrict__ x, const int* __restrict__ eidx,
    const float* __restrict__ attr, const uint16_t* __restrict__ w2frag,
    float* __restrict__ out, int E) {
  __shared__ __align__(16) uint16_t xb[64 * 64];  // bf16, swizzled, 8KB
  __shared__ __align__(16) float a_lds[64][20];   // padded to 80B rows, 5KB
  __shared__ int dst_lds[64];

  int tid = threadIdx.x;
  int w = tid >> 6, l = tid & 63, l16 = l & 15, lq = l >> 4;
  int tile0 = blockIdx.x * 64;
  int cnt = min(64, E - tile0);
  const int* srcp = eidx;
  const int* dstp = eidx + E;

  // ---- stage x (bf16, XOR-swizzled), a, dst ----
  {
    int row = tid >> 2, q = tid & 3;
    bool ok = row < cnt;
    int eg = tile0 + (ok ? row : 0);
    int sidx = srcp[eg];
    const float4* xs = (const float4*)(x + sidx * 64);
    float4 v[4];
#pragma unroll
    for (int j = 0; j < 4; ++j) v[j] = xs[q * 4 + j];
    uint4 c0, c1;
    c0.x = cvt_pk_bf16(v[0].x, v[0].y);
    c0.y = cvt_pk_bf16(v[0].z, v[0].w);
    c0.z = cvt_pk_bf16(v[1].x, v[1].y);
    c0.w = cvt_pk_bf16(v[1].z, v[1].w);
    c1.x = cvt_pk_bf16(v[2].x, v[2].y);
    c1.y = cvt_pk_bf16(v[2].z, v[2].w);
    c1.z = cvt_pk_bf16(v[3].x, v[3].y);
    c1.w = cvt_pk_bf16(v[3].z, v[3].w);
    int swz = (row & 7) << 4;
    *(uint4*)((char*)xb + ((row * 128 + q * 32) ^ swz)) = c0;
    *(uint4*)((char*)xb + ((row * 128 + q * 32 + 16) ^ swz)) = c1;
    *(float4*)&a_lds[row][q * 4] = ((const float4*)attr)[eg * 4 + q];
    if (tid < 64) dst_lds[tid] = dstp[tile0 + min(tid, cnt - 1)];
  }
  __syncthreads();

  // ---- A-frags once per tile (swizzled, conflict-free) ----
  short8 A[4][2];
  int swzr = (l16 & 7) << 4;
#pragma unroll
  for (int rt = 0; rt < 4; ++rt) {
    int rb = (rt * 16 + l16) * 128;
    A[rt][0] = *(const short8*)((const char*)xb + ((rb + lq * 16) ^ swzr));
    A[rt][1] = *(const short8*)((const char*)xb + ((rb + 64 + lq * 16) ^ swzr));
  }

  floatx4 acc[4];
#pragma unroll
  for (int rt = 0; rt < 4; ++rt) acc[rt] = (floatx4){0.f, 0.f, 0.f, 0.f};

  const short8* bp = (const short8*)w2frag;
  // bias-slot frags (a == 1), issued early so latency overlaps g-loop
  short8 Bb0 = bp[(32 * 4 + w) * 64 + l];
  short8 Bb1 = bp[(33 * 4 + w) * 64 + l];

#pragma unroll
  for (int g = 0; g < 4; ++g) {
    short8 Bf[8];
#pragma unroll
    for (int sg = 0; sg < 4; ++sg) {
      int s = g * 4 + sg;
      Bf[sg * 2 + 0] = bp[((s * 2 + 0) * 4 + w) * 64 + l];
      Bf[sg * 2 + 1] = bp[((s * 2 + 1) * 4 + w) * 64 + l];
    }
#pragma unroll
    for (int rt = 0; rt < 4; ++rt) {
      float4 av[4];
#pragma unroll
      for (int r = 0; r < 4; ++r)
        av[r] = *(const float4*)&a_lds[rt * 16 + lq * 4 + r][g * 4];
#pragma unroll
      for (int sg = 0; sg < 4; ++sg) {
        floatx4 y = (floatx4){0.f, 0.f, 0.f, 0.f};
        y = __builtin_amdgcn_mfma_f32_16x16x32_bf16(A[rt][0], Bf[sg * 2 + 0], y, 0, 0, 0);
        y = __builtin_amdgcn_mfma_f32_16x16x32_bf16(A[rt][1], Bf[sg * 2 + 1], y, 0, 0, 0);
        acc[rt][0] += f4_get(av[0], sg) * y[0];
        acc[rt][1] += f4_get(av[1], sg) * y[1];
        acc[rt][2] += f4_get(av[2], sg) * y[2];
        acc[rt][3] += f4_get(av[3], sg) * y[3];
      }
    }
  }
  // bias slot
#pragma unroll
  for (int rt = 0; rt < 4; ++rt) {
    floatx4 y = (floatx4){0.f, 0.f, 0.f, 0.f};
    y = __builtin_amdgcn_mfma_f32_16x16x32_bf16(A[rt][0], Bb0, y, 0, 0, 0);
    y = __builtin_amdgcn_mfma_f32_16x16x32_bf16(A[rt][1], Bb1, y, 0, 0, 0);
    acc[rt] += y;
  }

  // ---- line-coalesced atomic scatter: per instr 4 edges x 16 consec f ----
#pragma unroll
  for (int rt = 0; rt < 4; ++rt)
#pragma unroll
    for (int r = 0; r < 4; ++r) {
      int e = rt * 16 + lq * 4 + r;
      if (e < cnt) atomicAdd(&out[dst_lds[e] * 64 + w * 16 + l16], acc[rt][r]);
    }
}

__global__ __launch_bounds__(256) void ln_kernel(
    float* __restrict__ out, const float* __restrict__ gamma,
    const float* __restrict__ beta, int N) {
  int w = threadIdx.x >> 6, l = threadIdx.x & 63;
  int row = blockIdx.x * 4 + w;
  if (row >= N) return;
  float v = out[row * 64 + l];
  float s = v;
#pragma unroll
  for (int m = 32; m >= 1; m >>= 1) s += __shfl_xor(s, m);
  float mu = s * 0.015625f;
  float d = v - mu;
  float q = d * d;
#pragma unroll
  for (int m = 32; m >= 1; m >>= 1) q += __shfl_xor(q, m);
  float var = q * 0.015625f;
  out[row * 64 + l] = d * rsqrtf(var + 1e-5f) * gamma[l] + beta[l];
}

extern "C" void kernel_launch(void* const* d_in, const int* in_sizes, int n_in,
                              void* d_out, int out_size, void* d_ws, size_t ws_size,
                              hipStream_t stream) {
  const float* x      = (const float*)d_in[0];
  const int*   eidx   = (const int*)d_in[1];
  const float* attr   = (const float*)d_in[2];
  const float* W_edge = (const float*)d_in[3];
  const float* b_edge = (const float*)d_in[4];
  const float* W_root = (const float*)d_in[5];
  const float* bias   = (const float*)d_in[6];
  const float* W_res  = (const float*)d_in[7];
  const float* b_res  = (const float*)d_in[8];
  const float* gamma  = (const float*)d_in[9];
  const float* beta   = (const float*)d_in[10];
  int N = in_sizes[0] / 64;
  int E = in_sizes[1] / 2;
  float* out = (float*)d_out;
  uint16_t* w2frag = (uint16_t*)d_ws;

  int G1 = PREP_BLOCKS + (N + 63) / 64;
  k1_kernel<<<G1, 256, 0, stream>>>(x, W_edge, b_edge, W_root, bias, W_res,
                                    b_res, w2frag, out, N);
  int T = (E + 63) / 64;
  edge_kernel<<<T, 256, 0, stream>>>(x, eidx, attr, w2frag, out, E);
  ln_kernel<<<(N + 3) / 4, 256, 0, stream>>>(out, gamma, beta, N);
}